// Round 1
// baseline (7497.852 us; speedup 1.0000x reference)
//
#include <hip/hip_runtime.h>
#include <hip/hip_bf16.h>
#include <hip/hip_fp16.h>

// RSmatching: masked-gather GRU over selected tokens + 2-class softmax head.
// Phases:
//  1. cvt seq fp32->bf16, W_ih fp32->bf16                  (ws)
//  2. cvt W_hh fp32 -> fp16-pair "Wt4" layout [96][2304][4] (coalesced dot2 stream)
//  3. compact: per-sample list of selected positions (ballot prefix-sum)
//  4. gemm_xp: xp[32768][2304] = seq_bf16 @ W_ih^T + b_ih  (bf16 MFMA 16x16x32,
//     128x128x64 tiles, XOR-swizzled LDS, bf16 out)
//  5. rnn_kernel: 64 WGs x 768 thr; per sample, sequential scan over selected
//     steps; thread j owns h[j] and gate rows {j, j+768, j+1536};
//     hp dot via v_dot2_f32_f16 (fp16 inputs, fp32 accum); gates fp32;
//     classifier+softmax fused at the end.
// ws map (bytes, total ~199 MiB):
//   seq_bf16 [0, 50331648) | wih_bf16 +3538944 | xp_bf16 +150994944
//   | wt4 +3538944 | pos +131072 | cnt +256

#define NB 64
#define NS 512
#define ND 768
#define TD 2304   // 3*ND
#define KP 96     // 768/8 : uint4 (4x fp16-pairs) chunks along K

typedef __attribute__((ext_vector_type(2))) _Float16 half2v;
typedef __attribute__((ext_vector_type(4))) float f32x4;
typedef __attribute__((ext_vector_type(8))) short bf16x8;

union U32H2 { unsigned int u; half2v h; };

__device__ inline unsigned short f2bf(float f) {
  union { float f; unsigned u; } a; a.f = f;
  unsigned r = a.u + 0x7fff + ((a.u >> 16) & 1);
  return (unsigned short)(r >> 16);
}
__device__ inline float bf2f(unsigned short s) {
  union { unsigned u; float f; } a; a.u = ((unsigned)s) << 16;
  return a.f;
}
__device__ inline float dot2(unsigned int hu, unsigned int wu, float c) {
  U32H2 a, b; a.u = hu; b.u = wu;
  return __builtin_amdgcn_fdot2(a.h, b.h, c, false);
}

// ---------------- phase 1: fp32 -> bf16 (vectorized) ----------------
__global__ void cvt_f32_bf16(const float* __restrict__ in,
                             unsigned short* __restrict__ out, int n) {
  int i = (blockIdx.x * blockDim.x + threadIdx.x) * 4;
  int stride = gridDim.x * blockDim.x * 4;
  for (; i < n; i += stride) {
    float4 v = *(const float4*)(in + i);
    ushort4 o;
    o.x = f2bf(v.x); o.y = f2bf(v.y); o.z = f2bf(v.z); o.w = f2bf(v.w);
    *(ushort4*)(out + i) = o;
  }
}

// ---------------- phase 2: W_hh -> fp16-pair layout ----------------
// wt4[kkk][row][c] = half2(W_hh[row][8*kkk+2c], W_hh[row][8*kkk+2c+1])
__global__ void cvt_whh(const float* __restrict__ whh,
                        unsigned int* __restrict__ wt4, int n) {
  int idx = blockIdx.x * blockDim.x + threadIdx.x;
  if (idx >= n) return;
  int c   = idx & 3;
  int row = (idx >> 2) % TD;
  int kkk = idx / (4 * TD);
  int k0 = kkk * 8 + c * 2;
  U32H2 u;
  u.h = half2v{(_Float16)whh[row * ND + k0], (_Float16)whh[row * ND + k0 + 1]};
  wt4[idx] = u.u;
}

// ---------------- phase 3: compact selected positions ----------------
__global__ void compact_pos(const int* __restrict__ sot,
                            int* __restrict__ pos, int* __restrict__ cnt) {
  int b = blockIdx.x, t = threadIdx.x;          // 512 threads
  int m = (sot[b * NS + t] != 0) ? 1 : 0;
  unsigned long long ball = __ballot(m);
  int wid = t >> 6, lane = t & 63;
  __shared__ int wcnt[8];
  int prefix = __popcll(ball & ((1ull << lane) - 1ull));
  if (lane == 63) wcnt[wid] = __popcll(ball);
  __syncthreads();
  int base = 0;
  for (int w = 0; w < wid; ++w) base += wcnt[w];
  if (m) pos[b * NS + base + prefix] = t;
  if (t == 511) cnt[b] = base + wcnt[7];
}

// ---------------- phase 4: xp GEMM (bf16 MFMA) ----------------
// A[M=32768][K=768] bf16, B^T = W_ih[2304][768] bf16, C = xp bf16 + b_ih.
#define BM 128
#define BN 128
#define BKk 64
__global__ __launch_bounds__(256) void gemm_xp(
    const unsigned short* __restrict__ Ag,   // seq bf16
    const unsigned short* __restrict__ Bg,   // W_ih bf16 (row-major = B^T)
    const float* __restrict__ bias,          // b_ih fp32
    unsigned short* __restrict__ C) {        // xp bf16 [M][2304]
  __shared__ unsigned short lA[BM * BKk];
  __shared__ unsigned short lB[BN * BKk];
  const int tid = threadIdx.x;
  const int wid = tid >> 6, lane = tid & 63;
  const int m0 = blockIdx.x * BM, n0 = blockIdx.y * BN;
  const int wm = (wid & 1) * 64, wn = (wid >> 1) * 64;

  f32x4 acc[4][4];
#pragma unroll
  for (int i = 0; i < 4; ++i)
#pragma unroll
    for (int j = 0; j < 4; ++j) { f32x4 z = {0.f, 0.f, 0.f, 0.f}; acc[i][j] = z; }

  uint4 ra[4], rb[4];
  // stage: LDS[row][colb] holds global[row][colb ^ sw(row)] (XOR bank swizzle)
  auto stage_load = [&](int kt) {
#pragma unroll
    for (int c = 0; c < 4; ++c) {
      int idx = c * 256 + tid;
      int row = idx >> 3;
      int colb = (idx & 7) * 16;
      int scol = colb ^ ((row & 7) << 4);
      ra[c] = *(const uint4*)((const char*)(Ag + (size_t)(m0 + row) * ND + kt * BKk) + scol);
      rb[c] = *(const uint4*)((const char*)(Bg + (size_t)(n0 + row) * ND + kt * BKk) + scol);
    }
  };
  auto stage_write = [&]() {
#pragma unroll
    for (int c = 0; c < 4; ++c) {
      int idx = c * 256 + tid;
      int row = idx >> 3;
      int colb = (idx & 7) * 16;
      *(uint4*)((char*)lA + row * 128 + colb) = ra[c];
      *(uint4*)((char*)lB + row * 128 + colb) = rb[c];
    }
  };

  stage_load(0);
  for (int kt = 0; kt < 12; ++kt) {       // K = 768 = 12 * 64
    __syncthreads();
    stage_write();
    __syncthreads();
    if (kt < 11) stage_load(kt + 1);
#pragma unroll
    for (int kk = 0; kk < 2; ++kk) {
      bf16x8 af[4], bfr[4];
#pragma unroll
      for (int i = 0; i < 4; ++i) {
        int rowA = wm + i * 16 + (lane & 15);
        int kb = kk * 64 + (lane >> 4) * 16;     // byte offset in 128-B row
        af[i] = *(const bf16x8*)((const char*)lA + rowA * 128 + (kb ^ ((rowA & 7) << 4)));
        int rowB = wn + i * 16 + (lane & 15);
        bfr[i] = *(const bf16x8*)((const char*)lB + rowB * 128 + (kb ^ ((rowB & 7) << 4)));
      }
#pragma unroll
      for (int mi = 0; mi < 4; ++mi)
#pragma unroll
        for (int ni = 0; ni < 4; ++ni)
          acc[mi][ni] = __builtin_amdgcn_mfma_f32_16x16x32_bf16(
              af[mi], bfr[ni], acc[mi][ni], 0, 0, 0);
    }
  }
  // epilogue: C[row][col], row=(lane>>4)*4+j (+16*mi), col=lane&15 (+16*ni)
#pragma unroll
  for (int mi = 0; mi < 4; ++mi)
#pragma unroll
    for (int ni = 0; ni < 4; ++ni) {
      int col = n0 + wn + ni * 16 + (lane & 15);
      float bv = bias[col];
#pragma unroll
      for (int j = 0; j < 4; ++j) {
        int row = m0 + wm + mi * 16 + (lane >> 4) * 4 + j;
        C[(size_t)row * TD + col] = f2bf(acc[mi][ni][j] + bv);
      }
    }
}

// ---------------- phase 5: GRU scan + classifier ----------------
__global__ __launch_bounds__(768) void rnn_kernel(
    const unsigned short* __restrict__ xp,   // bf16 [B][S][TD]
    const unsigned int* __restrict__ wt4,    // fp16 pairs [96][TD][4]
    const float* __restrict__ b_hh,          // [TD]
    const int* __restrict__ pos, const int* __restrict__ cnt,
    const float* __restrict__ wcls,          // [2][768]
    const float* __restrict__ bcls,          // [2]
    float* __restrict__ out) {               // [B][2]
  const int b = blockIdx.x;
  const int j = threadIdx.x;                 // 0..767, owns h[j]
  __shared__ __align__(16) _Float16 hh[ND];
  __shared__ float red0[16], red1[16];

  float h = 0.f;
  hh[j] = (_Float16)0.f;
  const float br = b_hh[j], bz = b_hh[j + ND], bn = b_hh[j + 2 * ND];
  const int n = cnt[b];
  const unsigned int* wr = wt4 + (size_t)j * 4;
  const unsigned int* wz = wt4 + (size_t)(j + ND) * 4;
  const unsigned int* wq = wt4 + (size_t)(j + 2 * ND) * 4;
  __syncthreads();

  for (int k = 0; k < n; ++k) {
    const int t = pos[b * NS + k];
    const unsigned short* xrow = xp + ((size_t)b * NS + t) * TD;
    float xr = bf2f(xrow[j]);
    float xz = bf2f(xrow[j + ND]);
    float xn = bf2f(xrow[j + 2 * ND]);
    float ar = br, az = bz, an = bn;
    for (int kkk = 0; kkk < KP; ++kkk) {
      uint4 h4 = *(const uint4*)(hh + kkk * 8);          // LDS broadcast
      const size_t o = (size_t)kkk * TD * 4;
      uint4 w4;
      w4 = *(const uint4*)(wr + o);
      ar = dot2(h4.x, w4.x, ar); ar = dot2(h4.y, w4.y, ar);
      ar = dot2(h4.z, w4.z, ar); ar = dot2(h4.w, w4.w, ar);
      w4 = *(const uint4*)(wz + o);
      az = dot2(h4.x, w4.x, az); az = dot2(h4.y, w4.y, az);
      az = dot2(h4.z, w4.z, az); az = dot2(h4.w, w4.w, az);
      w4 = *(const uint4*)(wq + o);
      an = dot2(h4.x, w4.x, an); an = dot2(h4.y, w4.y, an);
      an = dot2(h4.z, w4.z, an); an = dot2(h4.w, w4.w, an);
    }
    float r = 1.f / (1.f + __expf(-(xr + ar)));
    float z = 1.f / (1.f + __expf(-(xz + az)));
    float nn = tanhf(xn + r * an);
    h = (1.f - z) * nn + z * h;
    __syncthreads();            // everyone done reading old hh
    hh[j] = (_Float16)h;
    __syncthreads();            // new hh visible
  }

  // classifier + softmax (L=2)
  float p0 = h * wcls[j];
  float p1 = h * wcls[ND + j];
#pragma unroll
  for (int off = 32; off; off >>= 1) {
    p0 += __shfl_down(p0, off);
    p1 += __shfl_down(p1, off);
  }
  int wv = j >> 6, lane = j & 63;
  if (lane == 0) { red0[wv] = p0; red1[wv] = p1; }
  __syncthreads();
  if (j == 0) {
    float l0 = bcls[0], l1 = bcls[1];
    for (int w = 0; w < 12; ++w) { l0 += red0[w]; l1 += red1[w]; }
    float mx = fmaxf(l0, l1);
    float e0 = __expf(l0 - mx), e1 = __expf(l1 - mx);
    float s = e0 + e1;
    out[b * 2 + 0] = e0 / s;
    out[b * 2 + 1] = e1 / s;
  }
}

extern "C" void kernel_launch(void* const* d_in, const int* in_sizes, int n_in,
                              void* d_out, int out_size, void* d_ws, size_t ws_size,
                              hipStream_t stream) {
  const float* seq  = (const float*)d_in[0];
  const int*   sot  = (const int*)d_in[1];
  const float* Wih  = (const float*)d_in[2];
  const float* Whh  = (const float*)d_in[3];
  const float* bih  = (const float*)d_in[4];
  const float* bhh  = (const float*)d_in[5];
  const float* Wcls = (const float*)d_in[6];
  const float* bcls = (const float*)d_in[7];
  float* out = (float*)d_out;

  char* ws = (char*)d_ws;
  unsigned short* seqb = (unsigned short*)(ws);                    // 50,331,648
  unsigned short* wihb = (unsigned short*)(ws + 50331648);         // +3,538,944
  unsigned short* xpb  = (unsigned short*)(ws + 53870592);         // +150,994,944
  unsigned int*   wt4  = (unsigned int*)(ws + 204865536);          // +3,538,944
  int*            pos  = (int*)(ws + 208404480);                   // +131,072
  int*            cntp = (int*)(ws + 208535552);                   // +256

  cvt_f32_bf16<<<4096, 256, 0, stream>>>(seq, seqb, NB * NS * ND);
  cvt_f32_bf16<<<1728, 256, 0, stream>>>(Wih, wihb, TD * ND);
  {
    int n = KP * TD * 4;
    cvt_whh<<<(n + 255) / 256, 256, 0, stream>>>(Whh, wt4, n);
  }
  compact_pos<<<NB, NS, 0, stream>>>(sot, pos, cntp);
  dim3 g(NB * NS / BM, TD / BN);   // 256 x 18
  gemm_xp<<<g, 256, 0, stream>>>(seqb, wihb, bih, xpb);
  rnn_kernel<<<NB, ND, 0, stream>>>(xpb, wt4, bhh, pos, cntp, Wcls, bcls, out);
}

// Round 2
// 2901.549 us; speedup vs baseline: 2.5841x; 2.5841x over previous
//
#include <hip/hip_runtime.h>
#include <hip/hip_bf16.h>
#include <hip/hip_fp16.h>

// RSmatching: masked-gather GRU + 2-class softmax head.
// v2: weight-stationary gang RNN.
//  - compact: per-sample selected positions + cntmax (device).
//  - gemm_xg: xg[k][s][2304] = bf16( seq[s][pos[s][k]] ) @ W_ih^T + b_ih,
//      A staged by pos-indirection with inline fp32->bf16, rows k>=cnt zero.
//      128x256 tiles, early-exit blocks with k >= cntmax.
//  - rnn_gang: 48 WGs x 256 thr. WG g owns dims [16g,16g+16): 48 W_hh rows
//      (r,z,n) resident in LDS (XOR-swizzled). Per step: hp = Wslice @ H
//      (MFMA bf16, B-operand = H[64][768] via agent-scope 8B loads),
//      gates fp32 in regs (lane owns 4 dims x 1 sample), h stored bf16 to
//      double-buffered H with agent-scope stores, then 48-WG device barrier
//      (sc1 counter). ~cntmax steps, lockstep, freeze via k<cnt[s].
//  - finalize: sum 48 partial logit slices, softmax.
// ws (~151 MiB): xg | wih_bf16 | whh_bf16 | pos | ctrl | H[2] | partial

#define NB 64
#define NS 512
#define ND 768
#define TD 2304
#define G  48

typedef __attribute__((ext_vector_type(4))) float f32x4;
typedef __attribute__((ext_vector_type(8))) short bf16x8;

__device__ inline unsigned short f2bf(float f) {
  union { float f; unsigned u; } a; a.f = f;
  unsigned r = a.u + 0x7fff + ((a.u >> 16) & 1);
  return (unsigned short)(r >> 16);
}
__device__ inline float bf2f(unsigned short s) {
  union { unsigned u; float f; } a; a.u = ((unsigned)s) << 16;
  return a.f;
}

// ---------------- fp32 -> bf16 ----------------
__global__ void cvt_f32_bf16(const float* __restrict__ in,
                             unsigned short* __restrict__ out, int n) {
  int i = (blockIdx.x * blockDim.x + threadIdx.x) * 4;
  int stride = gridDim.x * blockDim.x * 4;
  for (; i < n; i += stride) {
    float4 v = *(const float4*)(in + i);
    ushort4 o;
    o.x = f2bf(v.x); o.y = f2bf(v.y); o.z = f2bf(v.z); o.w = f2bf(v.w);
    *(ushort4*)(out + i) = o;
  }
}

// ---------------- compact selected positions ----------------
// ctrl[0..63]=cnt, ctrl[64]=cntmax, ctrl[96]=barrier counter
__global__ void compact_pos(const int* __restrict__ sot,
                            int* __restrict__ pos, int* __restrict__ ctrl) {
  int b = blockIdx.x, t = threadIdx.x;          // 512 threads
  int m = (sot[b * NS + t] != 0) ? 1 : 0;
  unsigned long long ball = __ballot(m);
  int wid = t >> 6, lane = t & 63;
  __shared__ int wcnt[8];
  int prefix = __popcll(ball & ((1ull << lane) - 1ull));
  if (lane == 63) wcnt[wid] = __popcll(ball);
  __syncthreads();
  int base = 0;
  for (int w = 0; w < wid; ++w) base += wcnt[w];
  if (m) pos[b * NS + base + prefix] = t;
  if (t == 511) {
    int total = base + wcnt[7];
    ctrl[b] = total;
    atomicMax(&ctrl[64], total);
  }
}

// ---------------- xg GEMM: gathered rows -> x-projection ----------------
// C[m=k*64+s][n] = bf16(seq[s][pos[s][k]]) . W_ih[n] + b_ih[n]
#define BM 128
#define BN 256
__global__ __launch_bounds__(256) void gemm_xg(
    const float* __restrict__ seq,           // fp32 [64][512][768]
    const int* __restrict__ pos,
    const int* __restrict__ ctrl,
    const unsigned short* __restrict__ Bg,   // W_ih bf16 [2304][768]
    const float* __restrict__ bias,          // b_ih fp32
    unsigned short* __restrict__ C) {        // xg bf16 [32768][2304]
  const int cntmax = ctrl[64];
  const int m0 = blockIdx.x * BM;
  if (m0 >= cntmax * 64) return;             // rows all beyond last step
  const int n0 = blockIdx.y * BN;
  __shared__ unsigned short lA[BM * 64];
  __shared__ unsigned short lB[BN * 64];
  const int tid = threadIdx.x;
  const int wid = tid >> 6, lane = tid & 63;
  const int wm = (wid & 1) * 64, wn = (wid >> 1) * 128;

  f32x4 acc[4][8];
#pragma unroll
  for (int i = 0; i < 4; ++i)
#pragma unroll
    for (int j = 0; j < 8; ++j) { f32x4 z = {0.f,0.f,0.f,0.f}; acc[i][j] = z; }

  for (int kt = 0; kt < 12; ++kt) {          // K = 768 = 12*64
    __syncthreads();
    // stage A: 128 rows x 64 k, pos-indirect gather + fp32->bf16
#pragma unroll
    for (int c = 0; c < 4; ++c) {
      int idx = c * 256 + tid;
      int r = idx >> 3, ch = idx & 7;
      int gm = m0 + r, ks = gm >> 6, ss = gm & 63;
      float4 v0 = {0,0,0,0}, v1 = {0,0,0,0};
      if (ks < ctrl[ss]) {
        int t = pos[ss * NS + ks];
        const float* src = seq + ((size_t)ss * NS + t) * ND + kt * 64 + ch * 8;
        v0 = *(const float4*)src;
        v1 = *(const float4*)(src + 4);
      }
      uint4 o;
      o.x = f2bf(v0.x) | ((unsigned)f2bf(v0.y) << 16);
      o.y = f2bf(v0.z) | ((unsigned)f2bf(v0.w) << 16);
      o.z = f2bf(v1.x) | ((unsigned)f2bf(v1.y) << 16);
      o.w = f2bf(v1.z) | ((unsigned)f2bf(v1.w) << 16);
      *(uint4*)((char*)lA + r * 128 + ((ch * 16) ^ ((r & 7) << 4))) = o;
    }
    // stage B: 256 rows x 64 k from bf16 W_ih
#pragma unroll
    for (int c = 0; c < 8; ++c) {
      int idx = c * 256 + tid;
      int r = idx >> 3, ch = idx & 7;
      uint4 v = *(const uint4*)(Bg + (size_t)(n0 + r) * ND + kt * 64 + ch * 8);
      *(uint4*)((char*)lB + r * 128 + ((ch * 16) ^ ((r & 7) << 4))) = v;
    }
    __syncthreads();
#pragma unroll
    for (int kk = 0; kk < 2; ++kk) {
      bf16x8 af[4], bfr[8];
      int kb = kk * 64 + (lane >> 4) * 16;
#pragma unroll
      for (int i = 0; i < 4; ++i) {
        int rowA = wm + i * 16 + (lane & 15);
        af[i] = *(const bf16x8*)((const char*)lA + rowA * 128 + (kb ^ ((rowA & 7) << 4)));
      }
#pragma unroll
      for (int i = 0; i < 8; ++i) {
        int rowB = wn + i * 16 + (lane & 15);
        bfr[i] = *(const bf16x8*)((const char*)lB + rowB * 128 + (kb ^ ((rowB & 7) << 4)));
      }
#pragma unroll
      for (int mi = 0; mi < 4; ++mi)
#pragma unroll
        for (int ni = 0; ni < 8; ++ni)
          acc[mi][ni] = __builtin_amdgcn_mfma_f32_16x16x32_bf16(
              af[mi], bfr[ni], acc[mi][ni], 0, 0, 0);
    }
  }
#pragma unroll
  for (int mi = 0; mi < 4; ++mi)
#pragma unroll
    for (int ni = 0; ni < 8; ++ni) {
      int col = n0 + wn + ni * 16 + (lane & 15);
      float bv = bias[col];
#pragma unroll
      for (int j = 0; j < 4; ++j) {
        int row = m0 + wm + mi * 16 + (lane >> 4) * 4 + j;
        C[(size_t)row * TD + col] = f2bf(acc[mi][ni][j] + bv);
      }
    }
}

// ---------------- gang barrier ----------------
__device__ inline void gangbar(int* bar, int target) {
  __syncthreads();
  if (threadIdx.x == 0) {
    __hip_atomic_fetch_add(bar, 1, __ATOMIC_ACQ_REL, __HIP_MEMORY_SCOPE_AGENT);
    while (__hip_atomic_load(bar, __ATOMIC_ACQUIRE, __HIP_MEMORY_SCOPE_AGENT) < target)
      __builtin_amdgcn_s_sleep(1);
  }
  __syncthreads();
}

// ---------------- weight-stationary gang RNN ----------------
__global__ __launch_bounds__(256) void rnn_gang(
    const unsigned short* __restrict__ xg,     // bf16 [512*64][2304]
    const unsigned short* __restrict__ whhb,   // bf16 [2304][768]
    const float* __restrict__ bhh,
    int* __restrict__ ctrl,
    unsigned short* __restrict__ Hb,           // bf16 [2][64][768]
    const float* __restrict__ wcls,            // fp32 [2][768]
    float* __restrict__ partial) {             // fp32 [48][64][2]
  extern __shared__ char lds[];                // 48 rows x 1536 B, swizzled
  const int wg = blockIdx.x, tid = threadIdx.x;
  const int w = tid >> 6, lane = tid & 63;
  const int d0 = wg * 16;

  // stage this WG's 48 W_hh rows (r,z,n x 16 dims) into LDS
  for (int c = tid; c < 48 * 96; c += 256) {
    int lrow = c / 96, cc = c - lrow * 96;
    int grow = (lrow >> 4) * ND + d0 + (lrow & 15);
    uint4 v = *(const uint4*)(whhb + (size_t)grow * ND + cc * 8);
    *(uint4*)(lds + lrow * 1536 + ((cc * 16) ^ ((lrow & 7) << 4))) = v;
  }

  const int s = w * 16 + (lane & 15);          // my sample
  const int dloc = (lane >> 4) * 4;            // my 4 dims within the 16
  const int d = d0 + dloc;
  const int cnt_s = ctrl[s];
  const int Kmax = ctrl[64];
  int* bar = ctrl + 96;
  const float4 br4 = *(const float4*)(bhh + d);
  const float4 bz4 = *(const float4*)(bhh + ND + d);
  const float4 bn4 = *(const float4*)(bhh + 2 * ND + d);
  float h4[4] = {0.f, 0.f, 0.f, 0.f};

  // zero my H slice in both buffers (agent scope)
  __hip_atomic_store((unsigned long long*)(Hb + (size_t)s * ND + d), 0ull,
                     __ATOMIC_RELAXED, __HIP_MEMORY_SCOPE_AGENT);
  __hip_atomic_store((unsigned long long*)(Hb + (size_t)(64 + s) * ND + d), 0ull,
                     __ATOMIC_RELAXED, __HIP_MEMORY_SCOPE_AGENT);
  int tgt = G;
  gangbar(bar, tgt);

  for (int k = 0; k < Kmax; ++k) {
    const int cur = k & 1;
    // xg prefetch (barrier-independent, plain loads)
    const unsigned short* xrow = xg + ((size_t)k * 64 + s) * TD + d;
    unsigned long long xrq = *(const unsigned long long*)(xrow);
    unsigned long long xzq = *(const unsigned long long*)(xrow + ND);
    unsigned long long xnq = *(const unsigned long long*)(xrow + 2 * ND);
    // B-operand: full H row for my sample (agent-scope 8B loads)
    const unsigned long long* hp8 = (const unsigned long long*)
        (Hb + (size_t)(cur * 64 + s) * ND + (lane >> 4) * 8);
    unsigned long long Bq[48];
#pragma unroll
    for (int kt = 0; kt < 24; ++kt) {
      Bq[2 * kt]     = __hip_atomic_load(hp8 + kt * 8,     __ATOMIC_RELAXED, __HIP_MEMORY_SCOPE_AGENT);
      Bq[2 * kt + 1] = __hip_atomic_load(hp8 + kt * 8 + 1, __ATOMIC_RELAXED, __HIP_MEMORY_SCOPE_AGENT);
    }
    f32x4 acc[3][2];
#pragma unroll
    for (int mi = 0; mi < 3; ++mi) {
      f32x4 z = {0.f, 0.f, 0.f, 0.f};
      acc[mi][0] = z; acc[mi][1] = z;
    }
#pragma unroll
    for (int kt = 0; kt < 24; ++kt) {
      union { unsigned long long q[2]; bf16x8 v; } bu;
      bu.q[0] = Bq[2 * kt]; bu.q[1] = Bq[2 * kt + 1];
#pragma unroll
      for (int mi = 0; mi < 3; ++mi) {
        int lrow = mi * 16 + (lane & 15);
        bf16x8 a = *(const bf16x8*)(lds + lrow * 1536 +
            ((kt * 64 + (lane >> 4) * 16) ^ ((lrow & 7) << 4)));
        acc[mi][kt & 1] = __builtin_amdgcn_mfma_f32_16x16x32_bf16(
            a, bu.v, acc[mi][kt & 1], 0, 0, 0);
      }
    }
    unsigned long long hq = 0;
#pragma unroll
    for (int j = 0; j < 4; ++j) {
      float ar = acc[0][0][j] + acc[0][1][j] + ((const float*)&br4)[j];
      float az = acc[1][0][j] + acc[1][1][j] + ((const float*)&bz4)[j];
      float an = acc[2][0][j] + acc[2][1][j] + ((const float*)&bn4)[j];
      float xr = bf2f((unsigned short)(xrq >> (16 * j)));
      float xz = bf2f((unsigned short)(xzq >> (16 * j)));
      float xn = bf2f((unsigned short)(xnq >> (16 * j)));
      float r = 1.f / (1.f + __expf(-(xr + ar)));
      float z = 1.f / (1.f + __expf(-(xz + az)));
      float nn = tanhf(xn + r * an);
      float hn = (1.f - z) * nn + z * h4[j];
      h4[j] = (k < cnt_s) ? hn : h4[j];
      hq |= ((unsigned long long)f2bf(h4[j])) << (16 * j);
    }
    __hip_atomic_store((unsigned long long*)(Hb + (size_t)((cur ^ 1) * 64 + s) * ND + d),
                       hq, __ATOMIC_RELAXED, __HIP_MEMORY_SCOPE_AGENT);
    tgt += G;
    gangbar(bar, tgt);
  }

  // classifier partials for my 4 dims
  const float4 w0 = *(const float4*)(wcls + d);
  const float4 w1 = *(const float4*)(wcls + ND + d);
  float p0 = h4[0] * w0.x + h4[1] * w0.y + h4[2] * w0.z + h4[3] * w0.w;
  float p1 = h4[0] * w1.x + h4[1] * w1.y + h4[2] * w1.z + h4[3] * w1.w;
  p0 += __shfl_xor(p0, 16); p0 += __shfl_xor(p0, 32);
  p1 += __shfl_xor(p1, 16); p1 += __shfl_xor(p1, 32);
  if (lane < 16) {
    partial[((size_t)wg * 64 + s) * 2]     = p0;
    partial[((size_t)wg * 64 + s) * 2 + 1] = p1;
  }
}

// ---------------- finalize: sum partials + softmax ----------------
__global__ void finalize(const float* __restrict__ partial,
                         const float* __restrict__ bcls,
                         float* __restrict__ out) {
  int s = threadIdx.x;                         // 64
  float l0 = bcls[0], l1 = bcls[1];
  for (int g = 0; g < G; ++g) {
    l0 += partial[((size_t)g * 64 + s) * 2];
    l1 += partial[((size_t)g * 64 + s) * 2 + 1];
  }
  float mx = fmaxf(l0, l1);
  float e0 = __expf(l0 - mx), e1 = __expf(l1 - mx);
  float inv = 1.f / (e0 + e1);
  out[2 * s]     = e0 * inv;
  out[2 * s + 1] = e1 * inv;
}

extern "C" void kernel_launch(void* const* d_in, const int* in_sizes, int n_in,
                              void* d_out, int out_size, void* d_ws, size_t ws_size,
                              hipStream_t stream) {
  const float* seq  = (const float*)d_in[0];
  const int*   sot  = (const int*)d_in[1];
  const float* Wih  = (const float*)d_in[2];
  const float* Whh  = (const float*)d_in[3];
  const float* bih  = (const float*)d_in[4];
  const float* bhh  = (const float*)d_in[5];
  const float* Wcls = (const float*)d_in[6];
  const float* bcls = (const float*)d_in[7];
  float* out = (float*)d_out;

  char* ws = (char*)d_ws;
  unsigned short* xg   = (unsigned short*)(ws);                   // 150,994,944
  unsigned short* wihb = (unsigned short*)(ws + 150994944);       // +3,538,944
  unsigned short* whhb = (unsigned short*)(ws + 154533888);       // +3,538,944
  int*            pos  = (int*)(ws + 158072832);                  // +131,072
  int*            ctrl = (int*)(ws + 158203904);                  // +512
  unsigned short* Hb   = (unsigned short*)(ws + 158204416);       // +196,608
  float*          part = (float*)(ws + 158401024);                // +24,576

  cvt_f32_bf16<<<1728, 256, 0, stream>>>(Wih, wihb, TD * ND);
  cvt_f32_bf16<<<1728, 256, 0, stream>>>(Whh, whhb, TD * ND);
  hipMemsetAsync(ctrl, 0, 512, stream);       // cnt, cntmax, barrier counter
  compact_pos<<<NB, NS, 0, stream>>>(sot, pos, ctrl);
  gemm_xg<<<dim3(NB * NS / BM, TD / BN), 256, 0, stream>>>(seq, pos, ctrl, wihb, bih, xg);
  rnn_gang<<<G, 256, 48 * 1536, stream>>>(xg, whhb, bhh, ctrl, Hb, Wcls, part);
  finalize<<<1, 64, 0, stream>>>(part, bcls, out);
}

// Round 3
// 2611.996 us; speedup vs baseline: 2.8705x; 1.1109x over previous
//
#include <hip/hip_runtime.h>
#include <hip/hip_bf16.h>

// RSmatching: masked-gather GRU + 2-class softmax head.
// v3: XCD-local gangs, flag-broadcast barrier, W_hh fragments in VGPRs.
//  - 8 gangs x 24 members (192 WGs x 384 thr). gang = blockIdx%8 (XCD-local
//    under round-robin dispatch; correctness is agent-scope regardless).
//  - gang g owns samples [8g,8g+8); member m owns h-dims [32m,32m+32)
//    (96 gate rows = 6 MFMA M-tiles, one per wave). W fragments in VGPRs.
//  - per step: poll 24 flags (padded lines) -> stage H[8][768] to swizzled
//    LDS -> 24 MFMA/wave -> gates (256 thr, h in regs) -> publish h slice
//    (agent stores) -> fence -> flag=k+2. Gangs fully independent.
//  - gemm_xg: xg[k][s][2304] = bf16(seq[s][pos[s][k]]) @ W_ih^T + b_ih.

#define NB 64
#define NS 512
#define ND 768
#define TD 2304
#define NM 24

typedef __attribute__((ext_vector_type(4))) float f32x4;
typedef __attribute__((ext_vector_type(8))) short bf16x8;

__device__ inline unsigned short f2bf(float f) {
  union { float f; unsigned u; } a; a.f = f;
  unsigned r = a.u + 0x7fff + ((a.u >> 16) & 1);
  return (unsigned short)(r >> 16);
}
__device__ inline float bf2f(unsigned short s) {
  union { unsigned u; float f; } a; a.u = ((unsigned)s) << 16;
  return a.f;
}

// ---------------- fp32 -> bf16 ----------------
__global__ void cvt_f32_bf16(const float* __restrict__ in,
                             unsigned short* __restrict__ out, int n) {
  int i = (blockIdx.x * blockDim.x + threadIdx.x) * 4;
  int stride = gridDim.x * blockDim.x * 4;
  for (; i < n; i += stride) {
    float4 v = *(const float4*)(in + i);
    ushort4 o;
    o.x = f2bf(v.x); o.y = f2bf(v.y); o.z = f2bf(v.z); o.w = f2bf(v.w);
    *(ushort4*)(out + i) = o;
  }
}

// ---------------- compact selected positions ----------------
// ctrl[0..63]=cnt, ctrl[64]=cntmax
__global__ void compact_pos(const int* __restrict__ sot,
                            int* __restrict__ pos, int* __restrict__ ctrl) {
  int b = blockIdx.x, t = threadIdx.x;          // 512 threads
  int m = (sot[b * NS + t] != 0) ? 1 : 0;
  unsigned long long ball = __ballot(m);
  int wid = t >> 6, lane = t & 63;
  __shared__ int wcnt[8];
  int prefix = __popcll(ball & ((1ull << lane) - 1ull));
  if (lane == 63) wcnt[wid] = __popcll(ball);
  __syncthreads();
  int base = 0;
  for (int w = 0; w < wid; ++w) base += wcnt[w];
  if (m) pos[b * NS + base + prefix] = t;
  if (t == 511) {
    int total = base + wcnt[7];
    ctrl[b] = total;
    atomicMax(&ctrl[64], total);
  }
}

// ---------------- xg GEMM: gathered rows -> x-projection ----------------
#define BM 128
#define BN 256
__global__ __launch_bounds__(256) void gemm_xg(
    const float* __restrict__ seq,           // fp32 [64][512][768]
    const int* __restrict__ pos,
    const int* __restrict__ ctrl,
    const unsigned short* __restrict__ Bg,   // W_ih bf16 [2304][768]
    const float* __restrict__ bias,          // b_ih fp32
    unsigned short* __restrict__ C) {        // xg bf16 [32768][2304]
  const int cntmax = ctrl[64];
  const int m0 = blockIdx.x * BM;
  if (m0 >= cntmax * 64) return;
  const int n0 = blockIdx.y * BN;
  __shared__ unsigned short lA[BM * 64];
  __shared__ unsigned short lB[BN * 64];
  const int tid = threadIdx.x;
  const int wid = tid >> 6, lane = tid & 63;
  const int wm = (wid & 1) * 64, wn = (wid >> 1) * 128;

  f32x4 acc[4][8];
#pragma unroll
  for (int i = 0; i < 4; ++i)
#pragma unroll
    for (int j = 0; j < 8; ++j) { f32x4 z = {0.f,0.f,0.f,0.f}; acc[i][j] = z; }

  for (int kt = 0; kt < 12; ++kt) {          // K = 768 = 12*64
    __syncthreads();
#pragma unroll
    for (int c = 0; c < 4; ++c) {
      int idx = c * 256 + tid;
      int r = idx >> 3, ch = idx & 7;
      int gm = m0 + r, ks = gm >> 6, ss = gm & 63;
      float4 v0 = {0,0,0,0}, v1 = {0,0,0,0};
      if (ks < ctrl[ss]) {
        int t = pos[ss * NS + ks];
        const float* src = seq + ((size_t)ss * NS + t) * ND + kt * 64 + ch * 8;
        v0 = *(const float4*)src;
        v1 = *(const float4*)(src + 4);
      }
      uint4 o;
      o.x = f2bf(v0.x) | ((unsigned)f2bf(v0.y) << 16);
      o.y = f2bf(v0.z) | ((unsigned)f2bf(v0.w) << 16);
      o.z = f2bf(v1.x) | ((unsigned)f2bf(v1.y) << 16);
      o.w = f2bf(v1.z) | ((unsigned)f2bf(v1.w) << 16);
      *(uint4*)((char*)lA + r * 128 + ((ch * 16) ^ ((r & 7) << 4))) = o;
    }
#pragma unroll
    for (int c = 0; c < 8; ++c) {
      int idx = c * 256 + tid;
      int r = idx >> 3, ch = idx & 7;
      uint4 v = *(const uint4*)(Bg + (size_t)(n0 + r) * ND + kt * 64 + ch * 8);
      *(uint4*)((char*)lB + r * 128 + ((ch * 16) ^ ((r & 7) << 4))) = v;
    }
    __syncthreads();
#pragma unroll
    for (int kk = 0; kk < 2; ++kk) {
      bf16x8 af[4], bfr[8];
      int kb = kk * 64 + (lane >> 4) * 16;
#pragma unroll
      for (int i = 0; i < 4; ++i) {
        int rowA = wm + i * 16 + (lane & 15);
        af[i] = *(const bf16x8*)((const char*)lA + rowA * 128 + (kb ^ ((rowA & 7) << 4)));
      }
#pragma unroll
      for (int i = 0; i < 8; ++i) {
        int rowB = wn + i * 16 + (lane & 15);
        bfr[i] = *(const bf16x8*)((const char*)lB + rowB * 128 + (kb ^ ((rowB & 7) << 4)));
      }
#pragma unroll
      for (int mi = 0; mi < 4; ++mi)
#pragma unroll
        for (int ni = 0; ni < 8; ++ni)
          acc[mi][ni] = __builtin_amdgcn_mfma_f32_16x16x32_bf16(
              af[mi], bfr[ni], acc[mi][ni], 0, 0, 0);
    }
  }
#pragma unroll
  for (int mi = 0; mi < 4; ++mi)
#pragma unroll
    for (int ni = 0; ni < 8; ++ni) {
      int col = n0 + wn + ni * 16 + (lane & 15);
      float bv = bias[col];
#pragma unroll
      for (int j = 0; j < 4; ++j) {
        int row = m0 + wm + mi * 16 + (lane >> 4) * 4 + j;
        C[(size_t)row * TD + col] = f2bf(acc[mi][ni][j] + bv);
      }
    }
}

// ---------------- XCD-local gang RNN ----------------
__global__ __launch_bounds__(384) void rnn_gang(
    const unsigned short* __restrict__ xg,     // bf16 [512*64][2304]
    const unsigned short* __restrict__ whhb,   // bf16 [2304][768]
    const float* __restrict__ bhh,
    const int* __restrict__ ctrl,
    int* __restrict__ flags,                   // [8][24] padded x16 ints
    unsigned short* __restrict__ Hb,           // bf16 [2][64][768]
    const float* __restrict__ wcls,            // fp32 [2][768]
    float* __restrict__ partial) {             // fp32 [24][64][2]
  const int g  = blockIdx.x & 7;               // gang (XCD under round-robin)
  const int m  = blockIdx.x >> 3;              // member 0..23
  const int d0 = m * 32;
  const int t  = threadIdx.x;
  const int w  = t >> 6;
  const int lane = t & 63;
  const int c  = lane & 15;
  const int kg = lane >> 4;

  __shared__ __align__(16) unsigned short Hl[8 * ND];   // 12 KB, swizzled
  __shared__ __align__(16) float hp[8][100];            // padded stride
  __shared__ __align__(16) unsigned short hstage[256];

  // my wave's M-tile W fragments -> registers (96 VGPR)
  const int lr = w * 16 + c;                   // local gate row 0..95
  const int grow = (lr >> 5) * ND + d0 + (lr & 31);
  bf16x8 afr[24];
#pragma unroll
  for (int kt = 0; kt < 24; ++kt)
    afr[kt] = *(const bf16x8*)(whhb + (size_t)grow * ND + kt * 32 + kg * 8);

  const int s  = (t >> 5) & 7;                 // gate-thread sample (t<256)
  const int d  = t & 31;                       // gate-thread dim
  const int sg = g * 8 + s;
  float br = 0.f, bz = 0.f, bn = 0.f, h = 0.f;
  int cnt_s = 0;
  if (t < 256) {
    br = bhh[d0 + d]; bz = bhh[ND + d0 + d]; bn = bhh[2 * ND + d0 + d];
    cnt_s = ctrl[sg];
  }
  int Kg = 0;
  for (int i = 0; i < 8; ++i) Kg = max(Kg, ctrl[g * 8 + i]);

  // zero my slice of buf0, publish flag=1
  if (t < 32) {
    unsigned long long* dst = (unsigned long long*)
        (Hb + ((size_t)(g * 8 + (t >> 2))) * ND + d0 + (t & 3) * 8);
    __hip_atomic_store(dst,     0ull, __ATOMIC_RELAXED, __HIP_MEMORY_SCOPE_AGENT);
    __hip_atomic_store(dst + 1, 0ull, __ATOMIC_RELAXED, __HIP_MEMORY_SCOPE_AGENT);
  }
  __threadfence();
  __syncthreads();
  if (t == 0)
    __hip_atomic_store(&flags[(g * NM + m) * 16], 1,
                       __ATOMIC_RELAXED, __HIP_MEMORY_SCOPE_AGENT);

  for (int k = 0; k < Kg; ++k) {
    // (A) xg prefetch (barrier-independent)
    float xr = 0.f, xz = 0.f, xn = 0.f;
    if (t < 256) {
      const unsigned short* xrow = xg + ((size_t)k * 64 + sg) * TD + d0 + d;
      xr = bf2f(xrow[0]); xz = bf2f(xrow[ND]); xn = bf2f(xrow[2 * ND]);
    }
    // (B) poll gang flags (one padded line per member)
    if (w == 0) {
      const int* fp = &flags[(g * NM + (lane < NM ? lane : 0)) * 16];
      while (true) {
        int v = __hip_atomic_load(fp, __ATOMIC_RELAXED, __HIP_MEMORY_SCOPE_AGENT);
        if (__all(lane >= NM || v >= k + 1)) break;
        __builtin_amdgcn_s_sleep(1);
      }
      __threadfence();
    }
    __syncthreads();
    // (C) stage H[8][768] -> swizzled LDS
    {
      const unsigned short* hsrc = Hb + ((size_t)(k & 1) * 64 + g * 8) * ND;
#pragma unroll
      for (int ii = 0; ii < 2; ++ii) {
        int i = t + ii * 384;
        int r = i / 96, c16 = i - r * 96;
        const unsigned long long* src =
            (const unsigned long long*)(hsrc + r * ND) + c16 * 2;
        unsigned long long a0 = __hip_atomic_load(src,     __ATOMIC_RELAXED, __HIP_MEMORY_SCOPE_AGENT);
        unsigned long long a1 = __hip_atomic_load(src + 1, __ATOMIC_RELAXED, __HIP_MEMORY_SCOPE_AGENT);
        union { unsigned long long q[2]; uint4 v; } u; u.q[0] = a0; u.q[1] = a1;
        *(uint4*)((char*)Hl + r * 1536 + ((c16 * 16) ^ ((r & 7) << 4))) = u.v;
      }
    }
    __syncthreads();
    // (D) MFMA: hp[96 rows][8 samples] for my tile
    f32x4 acc = {0.f, 0.f, 0.f, 0.f};
#pragma unroll
    for (int kt = 0; kt < 24; ++kt) {
      bf16x8 bfr = *(const bf16x8*)((const char*)Hl + (c & 7) * 1536 +
                    ((kt * 64 + kg * 16) ^ ((c & 7) << 4)));
      acc = __builtin_amdgcn_mfma_f32_16x16x32_bf16(afr[kt], bfr, acc, 0, 0, 0);
    }
    if (c < 8) *(f32x4*)&hp[c][w * 16 + kg * 4] = acc;
    __syncthreads();
    // (E) gates; h lives in gate-thread registers
    if (t < 256) {
      float ar = hp[s][d]      + br;
      float az = hp[s][32 + d] + bz;
      float an = hp[s][64 + d] + bn;
      float r  = 1.f / (1.f + __expf(-(xr + ar)));
      float z  = 1.f / (1.f + __expf(-(xz + az)));
      float nn = tanhf(xn + r * an);
      float hn = (1.f - z) * nn + z * h;
      if (k < cnt_s) h = hn;
      hstage[(s << 5) | d] = f2bf(h);
    }
    __syncthreads();
    // (F) publish h slice + flag
    if (t < 32) {
      const unsigned long long* sp =
          (const unsigned long long*)(hstage + (t >> 2) * 32 + (t & 3) * 8);
      unsigned long long q0 = sp[0], q1 = sp[1];
      unsigned long long* dst = (unsigned long long*)
          (Hb + ((size_t)((k + 1) & 1) * 64 + g * 8 + (t >> 2)) * ND + d0 + (t & 3) * 8);
      __hip_atomic_store(dst,     q0, __ATOMIC_RELAXED, __HIP_MEMORY_SCOPE_AGENT);
      __hip_atomic_store(dst + 1, q1, __ATOMIC_RELAXED, __HIP_MEMORY_SCOPE_AGENT);
    }
    if (w == 0) {
      __threadfence();
      if (t == 0)
        __hip_atomic_store(&flags[(g * NM + m) * 16], k + 2,
                           __ATOMIC_RELAXED, __HIP_MEMORY_SCOPE_AGENT);
    }
  }

  // classifier partials over my 32 dims
  if (t < 256) {
    float p0 = h * wcls[d0 + d];
    float p1 = h * wcls[ND + d0 + d];
#pragma unroll
    for (int off = 16; off; off >>= 1) {
      p0 += __shfl_xor(p0, off);
      p1 += __shfl_xor(p1, off);
    }
    if (d == 0) {
      partial[(size_t)(m * 64 + sg) * 2]     = p0;
      partial[(size_t)(m * 64 + sg) * 2 + 1] = p1;
    }
  }
}

// ---------------- finalize: sum partials + softmax ----------------
__global__ void finalize(const float* __restrict__ partial,
                         const float* __restrict__ bcls,
                         float* __restrict__ out) {
  int s = threadIdx.x;                         // 64
  float l0 = bcls[0], l1 = bcls[1];
  for (int m = 0; m < NM; ++m) {
    l0 += partial[(size_t)(m * 64 + s) * 2];
    l1 += partial[(size_t)(m * 64 + s) * 2 + 1];
  }
  float mx = fmaxf(l0, l1);
  float e0 = __expf(l0 - mx), e1 = __expf(l1 - mx);
  float inv = 1.f / (e0 + e1);
  out[2 * s]     = e0 * inv;
  out[2 * s + 1] = e1 * inv;
}

extern "C" void kernel_launch(void* const* d_in, const int* in_sizes, int n_in,
                              void* d_out, int out_size, void* d_ws, size_t ws_size,
                              hipStream_t stream) {
  const float* seq  = (const float*)d_in[0];
  const int*   sot  = (const int*)d_in[1];
  const float* Wih  = (const float*)d_in[2];
  const float* Whh  = (const float*)d_in[3];
  const float* bih  = (const float*)d_in[4];
  const float* bhh  = (const float*)d_in[5];
  const float* Wcls = (const float*)d_in[6];
  const float* bcls = (const float*)d_in[7];
  float* out = (float*)d_out;

  char* ws = (char*)d_ws;
  unsigned short* xg   = (unsigned short*)(ws);                   // 150,994,944
  unsigned short* wihb = (unsigned short*)(ws + 150994944);       // +3,538,944
  unsigned short* whhb = (unsigned short*)(ws + 154533888);       // +3,538,944
  int*            pos  = (int*)(ws + 158072832);                  // +131,072
  int*            ctrl = (int*)(ws + 158203904);                  // +512
  int*            flg  = (int*)(ws + 158204416);                  // +12,288
  unsigned short* Hb   = (unsigned short*)(ws + 158216704);       // +196,608
  float*          part = (float*)(ws + 158413312);                // +12,288

  cvt_f32_bf16<<<1728, 256, 0, stream>>>(Wih, wihb, TD * ND);
  cvt_f32_bf16<<<1728, 256, 0, stream>>>(Whh, whhb, TD * ND);
  hipMemsetAsync(ctrl, 0, 512 + 12288, stream);   // ctrl + flags
  compact_pos<<<NB, NS, 0, stream>>>(sot, pos, ctrl);
  gemm_xg<<<dim3(NB * NS / BM, TD / BN), 256, 0, stream>>>(seq, pos, ctrl, wihb, bih, xg);
  rnn_gang<<<192, 384, 0, stream>>>(xg, whhb, bhh, ctrl, flg, Hb, Wcls, part);
  finalize<<<1, 64, 0, stream>>>(part, bcls, out);
}

// Round 5
// 949.784 us; speedup vs baseline: 7.8943x; 2.7501x over previous
//
#include <hip/hip_runtime.h>
#include <hip/hip_bf16.h>

// RSmatching: masked-gather GRU + 2-class softmax head.
// v5: v3's static-gang structure + device-scope (sc0 sc1 / LLC-served) sync.
//  - 8 gangs x 24 members (192 WGs x 384 thr), gang = blockIdx&7 (static;
//    correctness placement-independent: all sync data goes through LLC).
//  - member m owns h-dims [32m,32m+32): 96 W_hh rows in VGPR fragments.
//  - per step: poll 24 flags (global_load sc0 sc1 -> LLC) -> stage H[8][768]
//    (sc0 sc1 loads) -> swizzled LDS -> 24 MFMA/wave -> gates -> publish h
//    slice (sc0 sc1 stores) -> s_waitcnt vmcnt(0) -> flag store (sc0 sc1).
//    NO __threadfence anywhere in the loop (no L2 writeback storms).
//  - watchdog: poll gives up after 2^20 iters (marks gang-dead, keeps
//    publishing) => kernel always terminates.
//  - gemm_xg: xg[k][s][2304] = bf16(seq[s][pos[s][k]]) @ W_ih^T + b_ih.

#define NB 64
#define NS 512
#define ND 768
#define TD 2304
#define NM 24

typedef __attribute__((ext_vector_type(4))) float f32x4;
typedef __attribute__((ext_vector_type(8))) short bf16x8;
typedef __attribute__((ext_vector_type(4))) unsigned int u32x4;

__device__ inline unsigned short f2bf(float f) {
  union { float f; unsigned u; } a; a.f = f;
  unsigned r = a.u + 0x7fff + ((a.u >> 16) & 1);
  return (unsigned short)(r >> 16);
}
__device__ inline float bf2f(unsigned short s) {
  union { unsigned u; float f; } a; a.u = ((unsigned)s) << 16;
  return a.f;
}

// ---- device-scope (LLC-served, L1+L2 bypass) access helpers ----
__device__ inline int load_flag(const int* p) {
  int v;
  asm volatile("global_load_dword %0, %1, off sc0 sc1\n\ts_waitcnt vmcnt(0)"
               : "=v"(v) : "v"(p) : "memory");
  return v;
}
__device__ inline void store_flag(int* p, int v) {
  asm volatile("global_store_dword %0, %1, off sc0 sc1"
               :: "v"(p), "v"(v) : "memory");
}
__device__ inline void store_h16(void* p, u32x4 v) {
  asm volatile("global_store_dwordx4 %0, %1, off sc0 sc1"
               :: "v"(p), "v"(v) : "memory");
}
__device__ inline void load2_h16(const void* p0, const void* p1,
                                 u32x4& a, u32x4& b) {
  asm volatile("global_load_dwordx4 %0, %2, off sc0 sc1\n\t"
               "global_load_dwordx4 %1, %3, off sc0 sc1\n\t"
               "s_waitcnt vmcnt(0)"
               : "=&v"(a), "=&v"(b) : "v"(p0), "v"(p1) : "memory");
}
__device__ inline void waitcnt_vm0() {
  asm volatile("s_waitcnt vmcnt(0)" ::: "memory");
}

// ---------------- fp32 -> bf16 ----------------
__global__ void cvt_f32_bf16(const float* __restrict__ in,
                             unsigned short* __restrict__ out, int n) {
  int i = (blockIdx.x * blockDim.x + threadIdx.x) * 4;
  int stride = gridDim.x * blockDim.x * 4;
  for (; i < n; i += stride) {
    float4 v = *(const float4*)(in + i);
    ushort4 o;
    o.x = f2bf(v.x); o.y = f2bf(v.y); o.z = f2bf(v.z); o.w = f2bf(v.w);
    *(ushort4*)(out + i) = o;
  }
}

// ---------------- compact selected positions ----------------
// ctrl[0..63]=cnt, ctrl[64]=cntmax
__global__ void compact_pos(const int* __restrict__ sot,
                            int* __restrict__ pos, int* __restrict__ ctrl) {
  int b = blockIdx.x, t = threadIdx.x;          // 512 threads
  int m = (sot[b * NS + t] != 0) ? 1 : 0;
  unsigned long long ball = __ballot(m);
  int wid = t >> 6, lane = t & 63;
  __shared__ int wcnt[8];
  int prefix = __popcll(ball & ((1ull << lane) - 1ull));
  if (lane == 63) wcnt[wid] = __popcll(ball);
  __syncthreads();
  int base = 0;
  for (int w = 0; w < wid; ++w) base += wcnt[w];
  if (m) pos[b * NS + base + prefix] = t;
  if (t == 511) {
    int total = base + wcnt[7];
    ctrl[b] = total;
    atomicMax(&ctrl[64], total);
  }
}

// ---------------- xg GEMM: gathered rows -> x-projection ----------------
#define BM 128
#define BN 256
__global__ __launch_bounds__(256) void gemm_xg(
    const float* __restrict__ seq,           // fp32 [64][512][768]
    const int* __restrict__ pos,
    const int* __restrict__ ctrl,
    const unsigned short* __restrict__ Bg,   // W_ih bf16 [2304][768]
    const float* __restrict__ bias,          // b_ih fp32
    unsigned short* __restrict__ C) {        // xg bf16 [32768][2304]
  const int cntmax = ctrl[64];
  const int m0 = blockIdx.x * BM;
  if (m0 >= cntmax * 64) return;
  const int n0 = blockIdx.y * BN;
  __shared__ unsigned short lA[BM * 64];
  __shared__ unsigned short lB[BN * 64];
  const int tid = threadIdx.x;
  const int wid = tid >> 6, lane = tid & 63;
  const int wm = (wid & 1) * 64, wn = (wid >> 1) * 128;

  f32x4 acc[4][8];
#pragma unroll
  for (int i = 0; i < 4; ++i)
#pragma unroll
    for (int j = 0; j < 8; ++j) { f32x4 z = {0.f,0.f,0.f,0.f}; acc[i][j] = z; }

  for (int kt = 0; kt < 12; ++kt) {          // K = 768 = 12*64
    __syncthreads();
#pragma unroll
    for (int c = 0; c < 4; ++c) {
      int idx = c * 256 + tid;
      int r = idx >> 3, ch = idx & 7;
      int gm = m0 + r, ks = gm >> 6, ss = gm & 63;
      float4 v0 = {0,0,0,0}, v1 = {0,0,0,0};
      if (ks < ctrl[ss]) {
        int t = pos[ss * NS + ks];
        const float* src = seq + ((size_t)ss * NS + t) * ND + kt * 64 + ch * 8;
        v0 = *(const float4*)src;
        v1 = *(const float4*)(src + 4);
      }
      uint4 o;
      o.x = f2bf(v0.x) | ((unsigned)f2bf(v0.y) << 16);
      o.y = f2bf(v0.z) | ((unsigned)f2bf(v0.w) << 16);
      o.z = f2bf(v1.x) | ((unsigned)f2bf(v1.y) << 16);
      o.w = f2bf(v1.z) | ((unsigned)f2bf(v1.w) << 16);
      *(uint4*)((char*)lA + r * 128 + ((ch * 16) ^ ((r & 7) << 4))) = o;
    }
#pragma unroll
    for (int c = 0; c < 8; ++c) {
      int idx = c * 256 + tid;
      int r = idx >> 3, ch = idx & 7;
      uint4 v = *(const uint4*)(Bg + (size_t)(n0 + r) * ND + kt * 64 + ch * 8);
      *(uint4*)((char*)lB + r * 128 + ((ch * 16) ^ ((r & 7) << 4))) = v;
    }
    __syncthreads();
#pragma unroll
    for (int kk = 0; kk < 2; ++kk) {
      bf16x8 af[4], bfr[8];
      int kb = kk * 64 + (lane >> 4) * 16;
#pragma unroll
      for (int i = 0; i < 4; ++i) {
        int rowA = wm + i * 16 + (lane & 15);
        af[i] = *(const bf16x8*)((const char*)lA + rowA * 128 + (kb ^ ((rowA & 7) << 4)));
      }
#pragma unroll
      for (int i = 0; i < 8; ++i) {
        int rowB = wn + i * 16 + (lane & 15);
        bfr[i] = *(const bf16x8*)((const char*)lB + rowB * 128 + (kb ^ ((rowB & 7) << 4)));
      }
#pragma unroll
      for (int mi = 0; mi < 4; ++mi)
#pragma unroll
        for (int ni = 0; ni < 8; ++ni)
          acc[mi][ni] = __builtin_amdgcn_mfma_f32_16x16x32_bf16(
              af[mi], bfr[ni], acc[mi][ni], 0, 0, 0);
    }
  }
#pragma unroll
  for (int mi = 0; mi < 4; ++mi)
#pragma unroll
    for (int ni = 0; ni < 8; ++ni) {
      int col = n0 + wn + ni * 16 + (lane & 15);
      float bv = bias[col];
#pragma unroll
      for (int j = 0; j < 4; ++j) {
        int row = m0 + wm + mi * 16 + (lane >> 4) * 4 + j;
        C[(size_t)row * TD + col] = f2bf(acc[mi][ni][j] + bv);
      }
    }
}

// ---------------- gang RNN (LLC-served sync, static gangs) ----------------
__global__ __launch_bounds__(384) void rnn_gang(
    const unsigned short* __restrict__ xg,     // bf16 [512*64][2304]
    const unsigned short* __restrict__ whhb,   // bf16 [2304][768]
    const float* __restrict__ bhh,
    const int* __restrict__ ctrl,
    int* __restrict__ flags,                   // [8][24] padded x16 ints
    unsigned short* __restrict__ Hb,           // bf16 [2][64][768]
    const float* __restrict__ wcls,            // fp32 [2][768]
    float* __restrict__ partial) {             // fp32 [24][64][2]
  const int g  = blockIdx.x & 7;               // gang
  const int m  = blockIdx.x >> 3;              // member 0..23
  const int d0 = m * 32;
  const int t  = threadIdx.x;
  const int w  = t >> 6;
  const int lane = t & 63;
  const int c  = lane & 15;
  const int kg = lane >> 4;

  __shared__ __align__(16) char Hl[8 * 1536];            // 12 KB, swizzled
  __shared__ __align__(16) float hp[8][100];             // padded stride
  __shared__ __align__(16) unsigned short hstage[256];

  // my wave's M-tile W fragments -> registers (96 VGPR)
  const int lr = w * 16 + c;                   // local gate row 0..95
  const int grow = (lr >> 5) * ND + d0 + (lr & 31);
  bf16x8 afr[24];
#pragma unroll
  for (int kt = 0; kt < 24; ++kt)
    afr[kt] = *(const bf16x8*)(whhb + (size_t)grow * ND + kt * 32 + kg * 8);

  const int s  = (t >> 5) & 7;                 // gate-thread sample (t<256)
  const int d  = t & 31;                       // gate-thread dim
  const int sg = g * 8 + s;
  float br = 0.f, bz = 0.f, bn = 0.f, h = 0.f;
  int cnt_s = 0;
  if (t < 256) {
    br = bhh[d0 + d]; bz = bhh[ND + d0 + d]; bn = bhh[2 * ND + d0 + d];
    cnt_s = ctrl[sg];
  }
  int Kg = 0;
  for (int i = 0; i < 8; ++i) Kg = max(Kg, ctrl[g * 8 + i]);
  int* FG = flags + g * NM * 16;
  const int pm = lane < NM ? lane : (lane < 2 * NM ? lane - NM : lane - 2 * NM);

  // zero both parities of my H slice (sc0 sc1), then publish flag=1
  if (t < 32) {
    u32x4 z = {0u, 0u, 0u, 0u};
    store_h16(Hb + ((size_t)(g * 8 + (t >> 2))) * ND + d0 + (t & 3) * 8, z);
    store_h16(Hb + ((size_t)(64 + g * 8 + (t >> 2))) * ND + d0 + (t & 3) * 8, z);
  }
  waitcnt_vm0();
  __syncthreads();
  if (t == 0) store_flag(&FG[m * 16], 1);

  int dead = 0;
  for (int k = 0; k < Kg; ++k) {
    // (A) xg load (plain cached; barrier-independent)
    float xr = 0.f, xz = 0.f, xn = 0.f;
    if (t < 256) {
      const unsigned short* xrow = xg + ((size_t)k * 64 + sg) * TD + d0 + d;
      xr = bf2f(xrow[0]); xz = bf2f(xrow[ND]); xn = bf2f(xrow[2 * ND]);
    }
    // (B) poll gang flags (sc0 sc1 -> LLC) with one-shot watchdog
    if (w == 0 && !dead) {
      const int* fp = &FG[pm * 16];
      int spins = 0;
      while (true) {
        int v = load_flag(fp);
        if (__all(v >= k + 1)) break;
        if (++spins > (1 << 20)) { dead = 1; break; }
      }
    }
    __syncthreads();
    // (C) stage H[8][768] -> swizzled LDS (sc0 sc1 loads)
    {
      const unsigned short* hsrc = Hb + ((size_t)(k & 1) * 64 + g * 8) * ND;
      int i1 = t + 384;
      int r0 = t / 96, c0 = t - r0 * 96;
      int r1 = i1 / 96, c1 = i1 - r1 * 96;
      u32x4 a0, a1;
      load2_h16(hsrc + r0 * ND + c0 * 8, hsrc + r1 * ND + c1 * 8, a0, a1);
      *(u32x4*)(Hl + r0 * 1536 + ((c0 * 16) ^ ((r0 & 7) << 4))) = a0;
      *(u32x4*)(Hl + r1 * 1536 + ((c1 * 16) ^ ((r1 & 7) << 4))) = a1;
    }
    __syncthreads();
    // (D) MFMA: hp[96 rows][8 samples] for my tile
    f32x4 acc = {0.f, 0.f, 0.f, 0.f};
#pragma unroll
    for (int kt = 0; kt < 24; ++kt) {
      bf16x8 bfr = *(const bf16x8*)(Hl + (c & 7) * 1536 +
                    ((kt * 64 + kg * 16) ^ ((c & 7) << 4)));
      acc = __builtin_amdgcn_mfma_f32_16x16x32_bf16(afr[kt], bfr, acc, 0, 0, 0);
    }
    if (c < 8) *(f32x4*)&hp[c][w * 16 + kg * 4] = acc;
    __syncthreads();
    // (E) gates; h lives in gate-thread registers
    if (t < 256) {
      float ar = hp[s][d]      + br;
      float az = hp[s][32 + d] + bz;
      float an = hp[s][64 + d] + bn;
      float r  = 1.f / (1.f + __expf(-(xr + ar)));
      float z  = 1.f / (1.f + __expf(-(xz + az)));
      float nn = tanhf(xn + r * an);
      float hn = (1.f - z) * nn + z * h;
      if (k < cnt_s) h = hn;
      hstage[(s << 5) | d] = f2bf(h);
    }
    __syncthreads();
    // (F) publish h slice (sc0 sc1) + vmcnt(0) + flag
    if (t < 32) {
      u32x4 q = *(const u32x4*)((const char*)hstage + (t >> 2) * 64 + (t & 3) * 16);
      store_h16(Hb + ((size_t)((k + 1) & 1) * 64 + g * 8 + (t >> 2)) * ND + d0 + (t & 3) * 8, q);
    }
    waitcnt_vm0();
    if (t == 0) store_flag(&FG[m * 16], k + 2);
  }

  // classifier partials over my 32 dims
  if (t < 256) {
    float p0 = h * wcls[d0 + d];
    float p1 = h * wcls[ND + d0 + d];
#pragma unroll
    for (int off = 16; off; off >>= 1) {
      p0 += __shfl_xor(p0, off);
      p1 += __shfl_xor(p1, off);
    }
    if (d == 0) {
      partial[(size_t)(m * 64 + sg) * 2]     = p0;
      partial[(size_t)(m * 64 + sg) * 2 + 1] = p1;
    }
  }
}

// ---------------- finalize: sum partials + softmax ----------------
__global__ void finalize(const float* __restrict__ partial,
                         const float* __restrict__ bcls,
                         float* __restrict__ out) {
  int s = threadIdx.x;                         // 64
  float l0 = bcls[0], l1 = bcls[1];
  for (int m = 0; m < NM; ++m) {
    l0 += partial[(size_t)(m * 64 + s) * 2];
    l1 += partial[(size_t)(m * 64 + s) * 2 + 1];
  }
  float mx = fmaxf(l0, l1);
  float e0 = __expf(l0 - mx), e1 = __expf(l1 - mx);
  float inv = 1.f / (e0 + e1);
  out[2 * s]     = e0 * inv;
  out[2 * s + 1] = e1 * inv;
}

extern "C" void kernel_launch(void* const* d_in, const int* in_sizes, int n_in,
                              void* d_out, int out_size, void* d_ws, size_t ws_size,
                              hipStream_t stream) {
  const float* seq  = (const float*)d_in[0];
  const int*   sot  = (const int*)d_in[1];
  const float* Wih  = (const float*)d_in[2];
  const float* Whh  = (const float*)d_in[3];
  const float* bih  = (const float*)d_in[4];
  const float* bhh  = (const float*)d_in[5];
  const float* Wcls = (const float*)d_in[6];
  const float* bcls = (const float*)d_in[7];
  float* out = (float*)d_out;

  char* ws = (char*)d_ws;
  unsigned short* xg   = (unsigned short*)(ws);                   // 150,994,944
  unsigned short* wihb = (unsigned short*)(ws + 150994944);       // +3,538,944
  unsigned short* whhb = (unsigned short*)(ws + 154533888);       // +3,538,944
  int*            pos  = (int*)(ws + 158072832);                  // +131,072
  int*            ctrl = (int*)(ws + 158203904);                  // +512
  int*            flg  = (int*)(ws + 158204416);                  // +12,288
  unsigned short* Hb   = (unsigned short*)(ws + 158216704);       // +196,608
  float*          part = (float*)(ws + 158413312);                // +12,288

  cvt_f32_bf16<<<1728, 256, 0, stream>>>(Wih, wihb, TD * ND);
  cvt_f32_bf16<<<1728, 256, 0, stream>>>(Whh, whhb, TD * ND);
  hipMemsetAsync(ctrl, 0, 512 + 12288, stream);   // ctrl + flags
  compact_pos<<<NB, NS, 0, stream>>>(sot, pos, ctrl);
  gemm_xg<<<dim3(NB * NS / BM, TD / BN), 256, 0, stream>>>(seq, pos, ctrl, wihb, bih, xg);
  rnn_gang<<<192, 384, 0, stream>>>(xg, whhb, bhh, ctrl, flg, Hb, Wcls, part);
  finalize<<<1, 64, 0, stream>>>(part, bcls, out);
}